// Round 1
// baseline (180.806 us; speedup 1.0000x reference)
//
#include <hip/hip_runtime.h>
#include <hip/hip_cooperative_groups.h>

namespace cg = cooperative_groups;

// DepthLossV2: sum over lower triangle (i>=j) of piecewise penalty on
// d0 = p[i]-p[j], s = (i-j)*a, a = STEP*z_spacing*nth_slice:
//   d0 < 0           -> -d0
//   0 <= d0 < 0.2s   -> 0.2s - d0
//   else             -> max(d0 - s, 0)
// With n0 = pj - pi and dij = i-j (float, exact):
//   e1 = fma(dij, 0.2a, n0)   (= 0.2s - d0)
//   t  = fma(dij, a,   n0)    (= s - d0)
//   c  = (n0 > 0) ? n0 : max3(e1, -t, 0)
// Single cooperative kernel: 1024 blocks grid-stride over 1056 tiles of
// 256 rows x 128 cols; per-thread register accumulation across tiles;
// one block reduction at the end; grid.sync(); block 0 reduces the 1024
// double partials and writes out. Non-cooperative 2-kernel fallback kept.
// loss = sum / (n*n)

typedef float f32x2 __attribute__((ext_vector_type(2)));

constexpr int ROWS = 256;   // threads per block, one i-row each
constexpr int COLS = 128;   // j-extent per tile
constexpr int GRID = 1024;  // 4 blocks/CU co-resident (launch_bounds(256,4))

__device__ __forceinline__ float block_tiles_sum(
    const float* __restrict__ p, float a, int ntiles, int tid, float* pjs)
{
    float a02 = 0.2f * a;
    f32x2 av   = { a,   a   };
    f32x2 a02v = { a02, a02 };
    f32x2 four = { 4.0f, 4.0f };
    f32x2 zero = { 0.0f, 0.0f };

    f32x2 acc2a = zero, acc2b = zero;

    for (int b = blockIdx.x; b < ntiles; b += GRID) {
        // tile b -> (ri, cj): row-tile ri has 2*ri+2 col-tiles, prefix = ri*(ri+1)
        int ri = (int)((sqrtf(4.0f * (float)b + 1.0f) - 1.0f) * 0.5f);
        while ((ri + 1) * (ri + 2) <= b) ++ri;
        while (ri * (ri + 1) > b) --ri;
        int cj = b - ri * (ri + 1);

        int i = ri * ROWS + tid;
        float pi = p[i];
        f32x2 pi2 = { pi, pi };

        int jbase = cj * COLS;
        if (tid < COLS / 4)
            ((float4*)pjs)[tid] = ((const float4*)(p + jbase))[tid];
        __syncthreads();

        float dij0 = (float)(i - jbase);          // exact in float (< 2^24)
        f32x2 d2a = { dij0,        dij0 - 1.0f }; // pairs (x,y)
        f32x2 d2b = { dij0 - 2.0f, dij0 - 3.0f }; // pairs (z,w)

        const float4* pj4 = (const float4*)pjs;

#define GROUP_BODY(VA, D2, ACC, MASKED)                               \
        {                                                             \
            f32x2 n0 = (VA) - pi2;                      /* v_pk_add */\
            f32x2 e1 = __builtin_elementwise_fma(D2, a02v, n0);       \
            f32x2 t  = __builtin_elementwise_fma(D2, av,   n0);       \
            f32x2 cp = __builtin_elementwise_max(                     \
                           __builtin_elementwise_max(e1, -t), zero);  \
            f32x2 c;                                                  \
            c.x = (n0.x > 0.0f) ? n0.x : cp.x;                        \
            c.y = (n0.y > 0.0f) ? n0.y : cp.y;                        \
            if (MASKED) {                                             \
                c.x = (D2.x >= 0.0f) ? c.x : 0.0f;                    \
                c.y = (D2.y >= 0.0f) ? c.y : 0.0f;                    \
            }                                                         \
            ACC += c;                                   /* v_pk_add */\
            D2  -= four;                                /* v_pk_add */\
        }

        if (cj < 2 * ri) {
            // fully interior: every j in tile < every i in tile
            #pragma unroll 8
            for (int q = 0; q < COLS / 4; ++q) {
                float4 v = pj4[q];
                f32x2 va = { v.x, v.y };
                f32x2 vb = { v.z, v.w };
                GROUP_BODY(va, d2a, acc2a, false)
                GROUP_BODY(vb, d2b, acc2b, false)
            }
        } else {
            // diagonal-touching tile: mask j > i via sign of dij
            #pragma unroll 8
            for (int q = 0; q < COLS / 4; ++q) {
                float4 v = pj4[q];
                f32x2 va = { v.x, v.y };
                f32x2 vb = { v.z, v.w };
                GROUP_BODY(va, d2a, acc2a, true)
                GROUP_BODY(vb, d2b, acc2b, true)
            }
        }
#undef GROUP_BODY
        __syncthreads();   // pjs reused next tile
    }

    float acc = (acc2a.x + acc2a.y) + (acc2b.x + acc2b.y);

    // wave-64 shuffle reduction, once per block (not per tile)
    for (int off = 32; off > 0; off >>= 1)
        acc += __shfl_down(acc, off, 64);

    __shared__ float wsum[ROWS / 64];
    if ((tid & 63) == 0) wsum[tid >> 6] = acc;
    __syncthreads();

    float bs = 0.0f;
    if (tid == 0)
        bs = (wsum[0] + wsum[1]) + (wsum[2] + wsum[3]);
    return bs;   // valid on tid==0 only
}

__global__ __launch_bounds__(ROWS, 4) void depth_loss_coop(
    const float* __restrict__ p,
    const float* __restrict__ zsp,
    const float* __restrict__ nsl,
    double* __restrict__ partials,
    float* __restrict__ out,
    int n)
{
    __shared__ __align__(16) float pjs[COLS];
    int tid = threadIdx.x;
    int nrt = n / ROWS;
    int ntiles = nrt * (nrt + 1);
    float a = zsp[0] * nsl[0];   // STEP == 1.0, a > 0

    float bs = block_tiles_sum(p, a, ntiles, tid, pjs);
    if (tid == 0) partials[blockIdx.x] = (double)bs;
    __threadfence();
    cg::this_grid().sync();

    if (blockIdx.x == 0) {
        // GRID == 1024 partials, 256 threads -> 4 each
        double acc = partials[tid]       + partials[tid + 256]
                   + partials[tid + 512] + partials[tid + 768];
        for (int off = 32; off > 0; off >>= 1)
            acc += __shfl_down(acc, off, 64);
        __shared__ double wsumd[ROWS / 64];
        if ((tid & 63) == 0) wsumd[tid >> 6] = acc;
        __syncthreads();
        if (tid == 0) {
            double inv_nn = 1.0 / ((double)n * (double)n);
            out[0] = (float)(((wsumd[0] + wsumd[1]) + (wsumd[2] + wsumd[3])) * inv_nn);
        }
    }
}

// ---- non-cooperative fallback (used only if cooperative launch rejected) ----

__global__ __launch_bounds__(ROWS, 4) void depth_loss_nosync(
    const float* __restrict__ p,
    const float* __restrict__ zsp,
    const float* __restrict__ nsl,
    double* __restrict__ partials,
    int n)
{
    __shared__ __align__(16) float pjs[COLS];
    int tid = threadIdx.x;
    int nrt = n / ROWS;
    int ntiles = nrt * (nrt + 1);
    float a = zsp[0] * nsl[0];

    float bs = block_tiles_sum(p, a, ntiles, tid, pjs);
    if (tid == 0) partials[blockIdx.x] = (double)bs;
}

__global__ __launch_bounds__(256) void finalize_kernel(
    const double* __restrict__ partials, int nblocks, float* __restrict__ out,
    double inv_nn)
{
    int tid = threadIdx.x;
    double acc = 0.0;
    for (int b = tid; b < nblocks; b += 256) acc += partials[b];
    for (int off = 32; off > 0; off >>= 1)
        acc += __shfl_down(acc, off, 64);
    __shared__ double wsum[4];
    if ((tid & 63) == 0) wsum[tid >> 6] = acc;
    __syncthreads();
    if (tid == 0)
        out[0] = (float)(((wsum[0] + wsum[1]) + (wsum[2] + wsum[3])) * inv_nn);
}

extern "C" void kernel_launch(void* const* d_in, const int* in_sizes, int n_in,
                              void* d_out, int out_size, void* d_ws, size_t ws_size,
                              hipStream_t stream) {
    const float* p   = (const float*)d_in[0];
    const float* zsp = (const float*)d_in[1];
    const float* nsl = (const float*)d_in[2];
    float* out = (float*)d_out;
    double* partials = (double*)d_ws;

    int n = in_sizes[0];              // 8192, divisible by ROWS

    void* args[] = { (void*)&p, (void*)&zsp, (void*)&nsl,
                     (void*)&partials, (void*)&out, (void*)&n };
    hipError_t err = hipLaunchCooperativeKernel(
        (const void*)depth_loss_coop, dim3(GRID), dim3(ROWS), args, 0, stream);

    if (err != hipSuccess) {
        double inv_nn = 1.0 / ((double)n * (double)n);
        depth_loss_nosync<<<GRID, ROWS, 0, stream>>>(p, zsp, nsl, partials, n);
        finalize_kernel<<<1, 256, 0, stream>>>(partials, GRID, out, inv_nn);
    }
}

// Round 2
// 67.716 us; speedup vs baseline: 2.6700x; 2.6700x over previous
//
#include <hip/hip_runtime.h>

// DepthLossV2: sum over lower triangle (i>=j) of piecewise penalty on
// d0 = p[i]-p[j], s = (i-j)*a, a = STEP*z_spacing*nth_slice:
//   d0 < 0           -> -d0
//   0 <= d0 < 0.2s   -> 0.2s - d0
//   else             -> max(d0 - s, 0)
// With n0 = pj - pi and dij = i-j (float, exact):
//   e1 = fma(dij, 0.2a, n0)   (= 0.2s - d0)
//   t  = fma(dij, a,   n0)    (= s - d0)
//   c  = (n0 > 0) ? n0 : max3(e1, -t, 0)
//
// Structure (round-2): 1024 blocks grid-stride over 1056 tiles of
// 256 rows x 128 cols; per-thread register accumulation across tiles;
// ONE block reduction at the end; double partial per block; tiny
// finalize kernel. NO cooperative grid.sync -- measured ~100us stall
// on MI355X (round 1: VALUBusy 4.9% over 106.8us) vs ~3us launch gap
// for a second dispatch.
// loss = sum / (n*n)

typedef float f32x2 __attribute__((ext_vector_type(2)));

constexpr int ROWS = 256;   // threads per block, one i-row each
constexpr int COLS = 128;   // j-extent per tile
constexpr int GRID = 1024;  // 4 blocks/CU co-resident (launch_bounds(256,4))

__device__ __forceinline__ float block_tiles_sum(
    const float* __restrict__ p, float a, int ntiles, int tid, float* pjs)
{
    float a02 = 0.2f * a;
    f32x2 av   = { a,   a   };
    f32x2 a02v = { a02, a02 };
    f32x2 four = { 4.0f, 4.0f };
    f32x2 zero = { 0.0f, 0.0f };

    f32x2 acc2a = zero, acc2b = zero;

    for (int b = blockIdx.x; b < ntiles; b += GRID) {
        // tile b -> (ri, cj): row-tile ri has 2*ri+2 col-tiles, prefix = ri*(ri+1)
        int ri = (int)((sqrtf(4.0f * (float)b + 1.0f) - 1.0f) * 0.5f);
        while ((ri + 1) * (ri + 2) <= b) ++ri;
        while (ri * (ri + 1) > b) --ri;
        int cj = b - ri * (ri + 1);

        int i = ri * ROWS + tid;
        float pi = p[i];
        f32x2 pi2 = { pi, pi };

        int jbase = cj * COLS;
        if (tid < COLS / 4)
            ((float4*)pjs)[tid] = ((const float4*)(p + jbase))[tid];
        __syncthreads();

        float dij0 = (float)(i - jbase);          // exact in float (< 2^24)
        f32x2 d2a = { dij0,        dij0 - 1.0f }; // pairs (x,y)
        f32x2 d2b = { dij0 - 2.0f, dij0 - 3.0f }; // pairs (z,w)

        const float4* pj4 = (const float4*)pjs;

#define GROUP_BODY(VA, D2, ACC, MASKED)                               \
        {                                                             \
            f32x2 n0 = (VA) - pi2;                      /* v_pk_add */\
            f32x2 e1 = __builtin_elementwise_fma(D2, a02v, n0);       \
            f32x2 t  = __builtin_elementwise_fma(D2, av,   n0);       \
            f32x2 cp = __builtin_elementwise_max(                     \
                           __builtin_elementwise_max(e1, -t), zero);  \
            f32x2 c;                                                  \
            c.x = (n0.x > 0.0f) ? n0.x : cp.x;                        \
            c.y = (n0.y > 0.0f) ? n0.y : cp.y;                        \
            if (MASKED) {                                             \
                c.x = (D2.x >= 0.0f) ? c.x : 0.0f;                    \
                c.y = (D2.y >= 0.0f) ? c.y : 0.0f;                    \
            }                                                         \
            ACC += c;                                   /* v_pk_add */\
            D2  -= four;                                /* v_pk_add */\
        }

        if (cj < 2 * ri) {
            // fully interior: every j in tile < every i in tile
            #pragma unroll 8
            for (int q = 0; q < COLS / 4; ++q) {
                float4 v = pj4[q];
                f32x2 va = { v.x, v.y };
                f32x2 vb = { v.z, v.w };
                GROUP_BODY(va, d2a, acc2a, false)
                GROUP_BODY(vb, d2b, acc2b, false)
            }
        } else {
            // diagonal-touching tile: mask j > i via sign of dij
            #pragma unroll 8
            for (int q = 0; q < COLS / 4; ++q) {
                float4 v = pj4[q];
                f32x2 va = { v.x, v.y };
                f32x2 vb = { v.z, v.w };
                GROUP_BODY(va, d2a, acc2a, true)
                GROUP_BODY(vb, d2b, acc2b, true)
            }
        }
#undef GROUP_BODY
        __syncthreads();   // pjs reused next tile
    }

    float acc = (acc2a.x + acc2a.y) + (acc2b.x + acc2b.y);

    // wave-64 shuffle reduction, once per block (not per tile)
    for (int off = 32; off > 0; off >>= 1)
        acc += __shfl_down(acc, off, 64);

    __shared__ float wsum[ROWS / 64];
    if ((tid & 63) == 0) wsum[tid >> 6] = acc;
    __syncthreads();

    float bs = 0.0f;
    if (tid == 0)
        bs = (wsum[0] + wsum[1]) + (wsum[2] + wsum[3]);
    return bs;   // valid on tid==0 only
}

__global__ __launch_bounds__(ROWS, 4) void depth_loss_main(
    const float* __restrict__ p,
    const float* __restrict__ zsp,
    const float* __restrict__ nsl,
    double* __restrict__ partials,
    int n)
{
    __shared__ __align__(16) float pjs[COLS];
    int tid = threadIdx.x;
    int nrt = n / ROWS;
    int ntiles = nrt * (nrt + 1);
    float a = zsp[0] * nsl[0];   // STEP == 1.0, a > 0

    float bs = block_tiles_sum(p, a, ntiles, tid, pjs);
    if (tid == 0) partials[blockIdx.x] = (double)bs;
}

__global__ __launch_bounds__(256) void finalize_kernel(
    const double* __restrict__ partials, int nblocks, float* __restrict__ out,
    double inv_nn)
{
    int tid = threadIdx.x;
    double acc = 0.0;
    for (int b = tid; b < nblocks; b += 256) acc += partials[b];
    for (int off = 32; off > 0; off >>= 1)
        acc += __shfl_down(acc, off, 64);
    __shared__ double wsum[4];
    if ((tid & 63) == 0) wsum[tid >> 6] = acc;
    __syncthreads();
    if (tid == 0)
        out[0] = (float)(((wsum[0] + wsum[1]) + (wsum[2] + wsum[3])) * inv_nn);
}

extern "C" void kernel_launch(void* const* d_in, const int* in_sizes, int n_in,
                              void* d_out, int out_size, void* d_ws, size_t ws_size,
                              hipStream_t stream) {
    const float* p   = (const float*)d_in[0];
    const float* zsp = (const float*)d_in[1];
    const float* nsl = (const float*)d_in[2];
    float* out = (float*)d_out;
    double* partials = (double*)d_ws;

    int n = in_sizes[0];              // 8192, divisible by ROWS
    double inv_nn = 1.0 / ((double)n * (double)n);

    depth_loss_main<<<GRID, ROWS, 0, stream>>>(p, zsp, nsl, partials, n);
    finalize_kernel<<<1, 256, 0, stream>>>(partials, GRID, out, inv_nn);
}